// Round 6
// baseline (65.197 us; speedup 1.0000x reference)
//
#include <hip/hip_runtime.h>

#define D_MODEL 2048
#define NUM_TILES 64
#define D_SLICE 32
#define TILES_PER_CLUSTER 8
#define NUM_CLUSTERS 8
#define GRID_PTS 16
#define LN_EPS 1e-5f
#define NBUCKET 64

// native 4-float vector
typedef float f32x4 __attribute__((ext_vector_type(4)));

// order-preserving float<->uint map for atomic min/max
__device__ __forceinline__ unsigned int encF(float f) {
    unsigned int u = __float_as_uint(f);
    return (u & 0x80000000u) ? ~u : (u | 0x80000000u);
}
__device__ __forceinline__ float decF(unsigned int u) {
    unsigned int b = (u & 0x80000000u) ? (u ^ 0x80000000u) : ~u;
    return __uint_as_float(b);
}

// Kernel A: slope_sign per dim + init bucketed tile min/max (ws is poisoned).
__global__ void kan_setup(const float* __restrict__ slopes,
                          float* __restrict__ sgn,
                          unsigned int* __restrict__ tminb,
                          unsigned int* __restrict__ tmaxb) {
    int d = blockIdx.x * blockDim.x + threadIdx.x;  // 0..4095
    if (d < NUM_TILES * NBUCKET) { tminb[d] = 0xFFFFFFFFu; tmaxb[d] = 0u; }
    if (d < D_MODEL) {
        const float* p = slopes + (size_t)d * GRID_PTS;
        float s = 0.f;
#pragma unroll
        for (int k = 0; k < GRID_PTS; ++k) s += p[k];
        float m = s * (1.0f / GRID_PTS);
        sgn[d] = (m > 0.f) ? 1.f : ((m < 0.f) ? -1.f : 0.f);
    }
}

// Kernel B: ONE WAVE PER TOKEN, zero LDS, zero barriers. Lane l owns dims
// {256c + 4l .. +3}, c=0..7 (coalesced float4). Tile 8c+k <-> chunk c,
// lane-group k (k = l>>3); cluster index == chunk index. All reductions are
// wave shuffles. NO runtime-indexed register arrays (rule #20): per-cluster
// winners kw0..kw7 and sums cs0..cs7 are named scalars; the chosen chunk's
// data is RELOADED from cache instead of selected from registers.
__launch_bounds__(256)
__global__ void kan_main(const float* __restrict__ x,
                         const float* __restrict__ gamma,
                         const float* __restrict__ beta,
                         const float* __restrict__ sgn,
                         float* __restrict__ out,
                         float* __restrict__ xn_slice,
                         int* __restrict__ tidx_out,
                         unsigned int* __restrict__ tminb,
                         unsigned int* __restrict__ tmaxb) {
    const int wid = threadIdx.x >> 6;
    const int l   = threadIdx.x & 63;
    const int k   = l >> 3;
    const int n   = blockIdx.x * 4 + wid;
    const size_t rowb = (size_t)n * D_MODEL;

    const float* xr = x + rowb + 4 * l;
    f32x4 xc0 = *(const f32x4*)(xr);
    f32x4 xc1 = *(const f32x4*)(xr + 256);
    f32x4 xc2 = *(const f32x4*)(xr + 512);
    f32x4 xc3 = *(const f32x4*)(xr + 768);
    f32x4 xc4 = *(const f32x4*)(xr + 1024);
    f32x4 xc5 = *(const f32x4*)(xr + 1280);
    f32x4 xc6 = *(const f32x4*)(xr + 1536);
    f32x4 xc7 = *(const f32x4*)(xr + 1792);

    // ---- out = x copy: plain cached stores, issued early ----
    float* orow = out + rowb + 4 * l;
    *(f32x4*)(orow)        = xc0;
    *(f32x4*)(orow + 256)  = xc1;
    *(f32x4*)(orow + 512)  = xc2;
    *(f32x4*)(orow + 768)  = xc3;
    *(f32x4*)(orow + 1024) = xc4;
    *(f32x4*)(orow + 1280) = xc5;
    *(f32x4*)(orow + 1536) = xc6;
    *(f32x4*)(orow + 1792) = xc7;

    // ---- fused sum + sumsq over 32 values, then 6-step wave butterfly ----
    float s = 0.f, q = 0.f;
#define ACC(V) { s += V.x + V.y + V.z + V.w; \
                 q += V.x*V.x + V.y*V.y + V.z*V.z + V.w*V.w; }
    ACC(xc0) ACC(xc1) ACC(xc2) ACC(xc3) ACC(xc4) ACC(xc5) ACC(xc6) ACC(xc7)
#undef ACC
#pragma unroll
    for (int off = 32; off > 0; off >>= 1) {
        s += __shfl_xor(s, off);
        q += __shfl_xor(q, off);
    }
    const float mu = s * (1.0f / D_MODEL);
    float var = q * (1.0f / D_MODEL) - mu * mu;
    var = fmaxf(var, 0.0f);
    const float rs = rsqrtf(var + LN_EPS);

    // ---- per-chunk: tile score (8-lane reduce), cluster sum (wave reduce),
    //      and per-cluster best-tile key-max. All results in NAMED scalars. ----
    const float* gp = gamma + 4 * l;
    const float* bp = beta + 4 * l;
    const float* sp = sgn + 4 * l;
    int cs0, cs1, cs2, cs3, cs4, cs5, cs6, cs7;
    int kw0, kw1, kw2, kw3, kw4, kw5, kw6, kw7;

#define CHUNK(c, XC, CS, KW)                                               \
    {                                                                      \
        f32x4 g  = *(const f32x4*)(gp + 256 * c);                          \
        f32x4 bb = *(const f32x4*)(bp + 256 * c);                          \
        f32x4 sg = *(const f32x4*)(sp + 256 * c);                          \
        float n0 = (XC.x - mu) * rs * g.x + bb.x;                          \
        float n1 = (XC.y - mu) * rs * g.y + bb.y;                          \
        float n2 = (XC.z - mu) * rs * g.z + bb.z;                          \
        float n3 = (XC.w - mu) * rs * g.w + bb.w;                          \
        int sc = ((n0 > 0.f) - (n0 < 0.f)) * (int)sg.x                     \
               + ((n1 > 0.f) - (n1 < 0.f)) * (int)sg.y                     \
               + ((n2 > 0.f) - (n2 < 0.f)) * (int)sg.z                     \
               + ((n3 > 0.f) - (n3 < 0.f)) * (int)sg.w;                    \
        sc += __shfl_xor(sc, 1);                                           \
        sc += __shfl_xor(sc, 2);                                           \
        sc += __shfl_xor(sc, 4);  /* tile score, replicated in group */    \
        int cm = sc;                                                       \
        cm += __shfl_xor(cm, 8);                                           \
        cm += __shfl_xor(cm, 16);                                          \
        cm += __shfl_xor(cm, 32); /* cluster sum, wave-uniform */          \
        CS = cm;                                                           \
        int key = ((sc + 64) << 3) | (7 - k);                              \
        key = max(key, __shfl_xor(key, 8));                                \
        key = max(key, __shfl_xor(key, 16));                               \
        key = max(key, __shfl_xor(key, 32)); /* wave-uniform */            \
        KW = 7 - (key & 7); /* winning k in cluster c (first-wins) */      \
    }
    CHUNK(0, xc0, cs0, kw0)
    CHUNK(1, xc1, cs1, kw1)
    CHUNK(2, xc2, cs2, kw2)
    CHUNK(3, xc3, cs3, kw3)
    CHUNK(4, xc4, cs4, kw4)
    CHUNK(5, xc5, cs5, kw5)
    CHUNK(6, xc6, cs6, kw6)
    CHUNK(7, xc7, cs7, kw7)
#undef CHUNK

    // ---- cluster argmax (first-wins), wave-uniform scalar chain ----
    int bc = 0, bv = cs0;
    if (cs1 > bv) { bv = cs1; bc = 1; }
    if (cs2 > bv) { bv = cs2; bc = 2; }
    if (cs3 > bv) { bv = cs3; bc = 3; }
    if (cs4 > bv) { bv = cs4; bc = 4; }
    if (cs5 > bv) { bv = cs5; bc = 5; }
    if (cs6 > bv) { bv = cs6; bc = 6; }
    if (cs7 > bv) { bv = cs7; bc = 7; }
    const int kwin = (bc == 0) ? kw0 : (bc == 1) ? kw1 : (bc == 2) ? kw2 :
                     (bc == 3) ? kw3 : (bc == 4) ? kw4 : (bc == 5) ? kw5 :
                     (bc == 6) ? kw6 : kw7;
    const int tile = bc * 8 + kwin;  // wave-uniform

    if (l == 0) tidx_out[n] = tile;

    // ---- chosen tile: the 8 lanes of group kwin reload their 16B from cache
    //      (x row just read; never mutated) and recompute xn. ----
    if (k == kwin) {
        const int doff = 256 * bc + 4 * l;  // dims of chunk bc for this lane
        f32x4 xs = *(const f32x4*)(x + rowb + doff);
        f32x4 g  = *(const f32x4*)(gamma + doff);
        f32x4 bb = *(const f32x4*)(beta + doff);
        f32x4 xn4;
        xn4.x = (xs.x - mu) * rs * g.x + bb.x;
        xn4.y = (xs.y - mu) * rs * g.y + bb.y;
        xn4.z = (xs.z - mu) * rs * g.z + bb.z;
        xn4.w = (xs.w - mu) * rs * g.w + bb.w;

        *(f32x4*)(xn_slice + (size_t)n * D_SLICE + 4 * (l & 7)) = xn4;

        float mn = fminf(fminf(xn4.x, xn4.y), fminf(xn4.z, xn4.w));
        float mx = fmaxf(fmaxf(xn4.x, xn4.y), fmaxf(xn4.z, xn4.w));
        mn = fminf(mn, __shfl_xor(mn, 1));
        mn = fminf(mn, __shfl_xor(mn, 2));
        mn = fminf(mn, __shfl_xor(mn, 4));
        mx = fmaxf(mx, __shfl_xor(mx, 1));
        mx = fmaxf(mx, __shfl_xor(mx, 2));
        mx = fmaxf(mx, __shfl_xor(mx, 4));
        if ((l & 7) == 0) {
            int bkt = n & (NBUCKET - 1);
            atomicMin(&tminb[tile * NBUCKET + bkt], encF(mn));
            atomicMax(&tmaxb[tile * NBUCKET + bkt], encF(mx));
        }
    }
}

// Kernel B2: reduce 64 buckets -> final per-tile min/max. One block, 64 thr.
__global__ void kan_reduce(const unsigned int* __restrict__ tminb,
                           const unsigned int* __restrict__ tmaxb,
                           unsigned int* __restrict__ tmin,
                           unsigned int* __restrict__ tmax) {
    int t = threadIdx.x;  // 0..63
    unsigned int mn = 0xFFFFFFFFu, mx = 0u;
#pragma unroll 4
    for (int b = 0; b < NBUCKET; ++b) {
        mn = min(mn, tminb[t * NBUCKET + b]);
        mx = max(mx, tmaxb[t * NBUCKET + b]);
    }
    tmin[t] = mn;
    tmax[t] = mx;
}

// Kernel C: one thread per (token, quad). Spline delta, float4 RMW on out.
__global__ void kan_apply(const float* __restrict__ xn_slice,
                          const int* __restrict__ tidx,
                          const float* __restrict__ bases,
                          const float* __restrict__ slopes,
                          const float* __restrict__ oscale,
                          const unsigned int* __restrict__ tmin,
                          const unsigned int* __restrict__ tmax,
                          float* __restrict__ out, int N) {
    int g = blockIdx.x * blockDim.x + threadIdx.x;
    if (g >= N * 8) return;
    int n = g >> 3;
    int qd = g & 7;  // quad of 4 dims: j = 4*qd..4*qd+3
    int t = tidx[n];
    f32x4 xn4 = *(const f32x4*)(xn_slice + (size_t)n * D_SLICE + qd * 4);
    float mn = decF(tmin[t]);
    float mx = decF(tmax[t]);
    float inv = 1.0f / (mx - mn + 1e-8f);
    float osc = oscale[t];

    float dl[4];
    float xnv[4] = {xn4.x, xn4.y, xn4.z, xn4.w};
#pragma unroll
    for (int e = 0; e < 4; ++e) {
        float u = (xnv[e] - mn) * inv;
        u = fminf(fmaxf(u, 0.0f), 1.0f - 1e-6f);
        int gi = (int)(u * (float)GRID_PTS);
        gi = min(max(gi, 0), GRID_PTS - 1);
        int j = qd * 4 + e;
        int off = (t * D_SLICE + j) * GRID_PTS + gi;
        float xl = (u - (float)gi * (1.0f / GRID_PTS)) * (float)GRID_PTS;
        dl[e] = (bases[off] + slopes[off] * xl) * osc;
    }
    size_t oi = (size_t)n * D_MODEL + t * D_SLICE + qd * 4;
    f32x4 o = *(f32x4*)(out + oi);
    o.x += dl[0]; o.y += dl[1]; o.z += dl[2]; o.w += dl[3];
    *(f32x4*)(out + oi) = o;
}

extern "C" void kernel_launch(void* const* d_in, const int* in_sizes, int n_in,
                              void* d_out, int out_size, void* d_ws, size_t ws_size,
                              hipStream_t stream) {
    const float* x      = (const float*)d_in[0];
    const float* gamma  = (const float*)d_in[1];
    const float* beta   = (const float*)d_in[2];
    const float* bases  = (const float*)d_in[3];
    const float* slopes = (const float*)d_in[4];
    const float* oscale = (const float*)d_in[5];
    float* out = (float*)d_out;
    const int N = in_sizes[0] / D_MODEL;  // 16384

    // workspace layout
    char* w = (char*)d_ws;
    unsigned int* tminb = (unsigned int*)w; w += NUM_TILES * NBUCKET * 4;
    unsigned int* tmaxb = (unsigned int*)w; w += NUM_TILES * NBUCKET * 4;
    unsigned int* tmin  = (unsigned int*)w; w += 256;
    unsigned int* tmax  = (unsigned int*)w; w += 256;
    float* sgn = (float*)w;  w += D_MODEL * sizeof(float);
    int* tidx = (int*)w;     w += (size_t)N * sizeof(int);
    float* xns = (float*)w;  w += (size_t)N * D_SLICE * sizeof(float);

    kan_setup<<<(NUM_TILES * NBUCKET + 255) / 256, 256, 0, stream>>>(slopes, sgn, tminb, tmaxb);
    kan_main<<<N / 4, 256, 0, stream>>>(x, gamma, beta, sgn, out, xns, tidx, tminb, tmaxb);
    kan_reduce<<<1, 64, 0, stream>>>(tminb, tmaxb, tmin, tmax);
    kan_apply<<<(N * 8 + 255) / 256, 256, 0, stream>>>(xns, tidx, bases, slopes,
                                                       oscale, tmin, tmax, out, N);
}